// Round 1
// baseline (410.838 us; speedup 1.0000x reference)
//
#include <hip/hip_runtime.h>
#include <stdint.h>

typedef unsigned short u16;
typedef unsigned long long u64;

#define N_ROWS 32768
#define DIM 256
#define K_CODES 8192
#define TAU 0.3f

// workspace offsets (bytes)
#define A_OFF     0ull            // 32768*256*2 = 16777216
#define B_OFF     16777216ull     // 8192*256*2  = 4194304
#define CN_OFF    20971520ull     // 8192*4
#define PART1_OFF 21004288ull     // 32768*4*8 = 1048576
#define PART2_OFF 22052864ull     // 32768*4*4 = 524288
#define IDX_OFF   22577152ull     // 32768*4
#define HIST_OFF  22708224ull     // 8192*4
#define CNT_OFF   22740992ull     // 16 (memset together with hist)
#define FLAG_OFF  22741008ull     // 32768*4
#define LOSS_OFF  22872080ull     // 8192*4
#define CBT_OFF   23068672ull     // 256*8192*4 = 8388608 (codebook transposed)
#define GMIN2_OFF 31457280ull     // 32768*8 = 262144

// output offsets (float elements)
#define OUT_Q 0
#define OUT_T 8388608
#define OUT_S 8421376

#define BM 128
#define BNT 64                      // per-iteration column tile
#define JSPLIT 4
#define NJC ((K_CODES / JSPLIT) / BNT)   // 32
#define RSPLIT 4     // recompute code-split

// packed sentinel: dist=+inf, idx=0xffffffff (any real (dist,idx) sorts below it)
#define PACK_INF ((((u64)0xFF800000u) << 32) | 0xFFFFFFFFull)

typedef _Float16 half8 __attribute__((ext_vector_type(8)));
typedef float floatx4 __attribute__((ext_vector_type(4)));

__device__ __forceinline__ void gload_lds16(const void* g, void* l) {
    __builtin_amdgcn_global_load_lds(
        (const __attribute__((address_space(1))) void*)g,
        (__attribute__((address_space(3))) void*)l,
        16, 0, 0);
}

__device__ __forceinline__ unsigned sortable(float v) {
    unsigned u = __float_as_uint(v);
    return (u & 0x80000000u) ? ~u : (u | 0x80000000u);
}
__device__ __forceinline__ float unsortable(unsigned u) {
    return (u & 0x80000000u) ? __uint_as_float(u & 0x7fffffffu) : __uint_as_float(~u);
}
__device__ __forceinline__ u64 shfl64x(u64 v, int m) {
    return ((u64)(unsigned)__shfl_xor((int)(v >> 32), m, 64) << 32) |
           (unsigned)__shfl_xor((int)(v & 0xffffffffu), m, 64);
}
__device__ __forceinline__ u64 u64min(u64 a, u64 b) { return a < b ? a : b; }
__device__ __forceinline__ u64 u64max(u64 a, u64 b) { return a > b ? a : b; }

// fp32 -> f16 cast for inputs and codebook; fused ||c||^2.
__global__ void prep(const float* __restrict__ inp, const float* __restrict__ cb,
                     u16* __restrict__ A, u16* __restrict__ B, float* __restrict__ cn) {
    int g = blockIdx.x * 256 + threadIdx.x;       // 40960 rows * 32 threads
    int row = g >> 5;
    int kc = (g & 31) << 3;
    bool isA = row < N_ROWS;
    const float* src = isA ? inp + (size_t)row * DIM + kc
                           : cb + (size_t)(row - N_ROWS) * DIM + kc;
    u16* dst = isA ? A + (size_t)row * DIM + kc
                   : B + (size_t)(row - N_ROWS) * DIM + kc;
    float4 x0 = *(const float4*)(src);
    float4 x1 = *(const float4*)(src + 4);
    float xs[8] = {x0.x, x0.y, x0.z, x0.w, x1.x, x1.y, x1.z, x1.w};
    half8 hv;
    float s = 0.f;
#pragma unroll
    for (int i = 0; i < 8; ++i) {
        hv[i] = (_Float16)xs[i];
        s = fmaf(xs[i], xs[i], s);
    }
    *(half8*)(dst) = hv;
    if (!isA) {
#pragma unroll
        for (int m = 1; m <= 16; m <<= 1) s += __shfl_xor(s, m, 64);
        if ((g & 31) == 0) cn[row - N_ROWS] = s;
    }
}

// LDS-tiled transpose: cbT[d][j] = cb[j][d]. 64x64 tiles.
__global__ void transpose_cb(const float* __restrict__ cb, float* __restrict__ cbT) {
    __shared__ float tile[64][65];
    const int tid = threadIdx.x;
    const int tj = blockIdx.x * 64;     // code-tile base
    const int td = blockIdx.y * 64;     // dim-tile base
    const int c = (tid & 15) * 4;
    const int r0 = tid >> 4;
#pragma unroll
    for (int p = 0; p < 4; ++p) {
        int r = p * 16 + r0;
        float4 v = *(const float4*)(cb + (size_t)(tj + r) * DIM + td + c);
        tile[r][c] = v.x; tile[r][c + 1] = v.y; tile[r][c + 2] = v.z; tile[r][c + 3] = v.w;
    }
    __syncthreads();
#pragma unroll
    for (int p = 0; p < 4; ++p) {
        int rr = p * 16 + r0;
        float4 w = {tile[c][rr], tile[c + 1][rr], tile[c + 2][rr], tile[c + 3][rr]};
        *(float4*)(cbT + (size_t)(td + rr) * K_CODES + tj + c) = w;
    }
}

// B-tile staging: 64 cols x 256 k f16 = 32 KB, XOR-swizzled 16B chunks.
// 512 threads x 4 rounds x 16B. LDS dest is linear (wave-uniform + lane*16);
// swizzle applied on the GLOBAL source address (both-sides-or-neither rule).
#define STAGE_B(BUFP, JCV)                                                    \
    {                                                                         \
        const u16* bsrc = B + (size_t)(jBase + (JCV) * BNT) * DIM;            \
        _Pragma("unroll")                                                     \
        for (int r_ = 0; r_ < 4; ++r_) {                                      \
            int idx_ = r_ * 512 + tid;                                        \
            int col_ = idx_ >> 5;                                             \
            int sc_ = idx_ & 31;                                              \
            int csrc_ = (sc_ & 24) | ((sc_ & 7) ^ (col_ & 7));                \
            gload_lds16(bsrc + (size_t)col_ * DIM + csrc_ * 8,                \
                        (char*)(BUFP) + idx_ * 16);                           \
        }                                                                     \
    }

// top-2 insert for tile JT using acc + its ||c||^2 value CNV.
// d1<=d2 invariant => new d2 = med3(d1, d2, val). 5 VALU/element.
#define TOP2(JT, CNV)                                                         \
    {                                                                         \
        unsigned jj = (unsigned)(jBase + (JT) * BNT + colLoc);                \
        _Pragma("unroll")                                                     \
        for (int mi_ = 0; mi_ < 4; ++mi_) {                                   \
            _Pragma("unroll")                                                 \
            for (int r_ = 0; r_ < 4; ++r_) {                                  \
                int tr_ = mi_ * 4 + r_;                                       \
                float val_ = fmaf(-2.0f, acc[mi_][r_], (CNV));                \
                float nd2_ = __builtin_amdgcn_fmed3f(d1[tr_], d2[tr_], val_); \
                bool lt_ = val_ < d1[tr_];                                    \
                d1[tr_] = fminf(d1[tr_], val_);                               \
                idxr[tr_] = lt_ ? jj : idxr[tr_];                             \
                d2[tr_] = nd2_;                                               \
            }                                                                 \
        }                                                                     \
    }

// pass 1: A resident in VGPRs (loaded once, fragment layout, direct from
// global); B double-buffered in LDS, staged with counted vmcnt so loads stay
// in flight across barriers (T3/T4). Per-row top-2 over 2048-col slice.
__launch_bounds__(512, 2)
__global__ void vq_pass1(const u16* __restrict__ A, const u16* __restrict__ B,
                         const float* __restrict__ cn,
                         u64* __restrict__ part1, float* __restrict__ part2) {
    __shared__ __align__(16) _Float16 lsB[2][BNT * DIM];   // 2 x 32 KiB

    const int tid = threadIdx.x;
    const int lane = tid & 63;
    const int w = tid >> 6;          // 0..7
    const int wm = w >> 2;           // 64-row half
    const int wn = w & 3;            // 16-col slice
    const int l15 = lane & 15;
    const int quad = lane >> 4;
    const int xm = l15 & 7;
    const int colLoc = wn * 16 + l15;
    const int rowBase = blockIdx.x * BM;
    const int jBase = blockIdx.y * (K_CODES / JSPLIT);

    // ---- prologue: tile-0 stage + cn(0) form the oldest VMEM group ----
    STAGE_B(lsB[0], 0);
    float cn_c = cn[jBase + colLoc];

    // A fragments in registers: af[mi][ks], row = rowBase+wm*64+mi*16+l15,
    // k = ks*32 + quad*8 (same logical layout the old swizzled LDS path gave).
    half8 af[4][8];
    {
        const u16* aRow = A + (size_t)(rowBase + wm * 64 + l15) * DIM + quad * 8;
#pragma unroll
        for (int mi = 0; mi < 4; ++mi)
#pragma unroll
            for (int ks = 0; ks < 8; ++ks)
                af[mi][ks] = *(const half8*)(aRow + (size_t)mi * 16 * DIM + ks * 32);
    }

    float d1[16], d2[16];
    unsigned idxr[16];
#pragma unroll
    for (int i = 0; i < 16; ++i) {
        d1[i] = __builtin_inff(); d2[i] = __builtin_inff(); idxr[i] = 0xffffffffu;
    }
    floatx4 acc[4];
    float cn_p = 0.f, cn_n = 0.f;

#pragma unroll 1
    for (int jc = 0; jc < NJC; ++jc) {
        // issue next tile's 4 stage loads + 1 cn load (stay in flight past barrier)
        if (jc < NJC - 1) {
            STAGE_B(lsB[(jc + 1) & 1], jc + 1);
            cn_n = cn[jBase + (jc + 1) * BNT + colLoc];
        }
        // top-2 for previous tile's acc: VALU hides under in-flight loads
        if (jc > 0) TOP2(jc - 1, cn_p);
        // wait only for the PREVIOUS group (this tile's data); leave newest 5 in flight
        if (jc < NJC - 1) asm volatile("s_waitcnt vmcnt(5)" ::: "memory");
        else              asm volatile("s_waitcnt vmcnt(0)" ::: "memory");
        __builtin_amdgcn_s_barrier();

        const _Float16* bcur = lsB[jc & 1];
#pragma unroll
        for (int mi = 0; mi < 4; ++mi) acc[mi] = (floatx4){0.f, 0.f, 0.f, 0.f};
#pragma unroll
        for (int ks = 0; ks < 8; ++ks) {
            const int c = ks * 4 + quad;
            const int scw = (c & 24) | ((c & 7) ^ xm);
            half8 bfv = *(const half8*)((const char*)bcur + colLoc * 512 + scw * 16);
#pragma unroll
            for (int mi = 0; mi < 4; ++mi)
                acc[mi] = __builtin_amdgcn_mfma_f32_16x16x32_f16(
                    af[mi][ks], bfv, acc[mi], 0, 0, 0);
        }
        __builtin_amdgcn_s_barrier();   // all waves done reading bcur
        cn_p = cn_c; cn_c = cn_n;
    }
    TOP2(NJC - 1, cn_p);

    // pack (cold) and merge across the 16 lanes sharing each row
    u64 m1[16];
#pragma unroll
    for (int tr = 0; tr < 16; ++tr)
        m1[tr] = ((u64)sortable(d1[tr]) << 32) | idxr[tr];
#pragma unroll
    for (int m = 1; m <= 8; m <<= 1)
#pragma unroll
        for (int tr = 0; tr < 16; ++tr) {
            u64 o1 = shfl64x(m1[tr], m);
            float o2 = __shfl_xor(d2[tr], m, 64);
            u64 n1 = u64min(m1[tr], o1);
            float big = unsortable((unsigned)(u64max(m1[tr], o1) >> 32));
            d2[tr] = fminf(big, fminf(d2[tr], o2));
            m1[tr] = n1;
        }

    // merge the 4 column-slice waves via LDS (overlaid on buf0; loop is done)
    u64* t1 = (u64*)lsB[0];                                   // [4][BM] = 4 KB
    float* t2 = (float*)((char*)lsB[0] + 4 * BM * 8);         // [4][BM] = 2 KB
    __syncthreads();
    if (l15 == 0) {
#pragma unroll
        for (int tr = 0; tr < 16; ++tr) {
            int rl = wm * 64 + (tr >> 2) * 16 + quad * 4 + (tr & 3);
            t1[wn * BM + rl] = m1[tr];
            t2[wn * BM + rl] = d2[tr];
        }
    }
    __syncthreads();
    if (tid < BM) {
        u64 b1 = t1[tid];
        float b2 = t2[tid];
#pragma unroll
        for (int y = 1; y < 4; ++y) {
            u64 o1 = t1[y * BM + tid];
            float o2 = t2[y * BM + tid];
            u64 n1 = u64min(b1, o1);
            float big = unsortable((unsigned)(u64max(b1, o1) >> 32));
            b2 = fminf(big, fminf(b2, o2));
            b1 = n1;
        }
        size_t p = (size_t)(rowBase + tid) * JSPLIT + blockIdx.y;
        part1[p] = b1;
        part2[p] = b2;
    }
}

// merge JSPLIT partial top-2s; emit idx + flag near-ties for exact recompute
__global__ void vq_merge(const u64* __restrict__ part1, const float* __restrict__ part2,
                         unsigned* __restrict__ idx32,
                         int* __restrict__ flaglist, int* __restrict__ cnt) {
    int row = blockIdx.x * 256 + threadIdx.x;
    u64 m1 = PACK_INF;
    float f2 = __builtin_inff();
#pragma unroll
    for (int y = 0; y < JSPLIT; ++y) {
        u64 p1 = part1[(size_t)row * JSPLIT + y];
        float p2 = part2[(size_t)row * JSPLIT + y];
        u64 n1 = u64min(m1, p1);
        float big = unsortable((unsigned)(u64max(m1, p1) >> 32));
        f2 = fminf(big, fminf(f2, p2));
        m1 = n1;
    }
    idx32[row] = (unsigned)(m1 & 0xffffffffu);
    float f1 = unsortable((unsigned)(m1 >> 32));
    if (f2 - f1 < TAU) {
        int p = atomicAdd(cnt, 1);
        flaglist[p] = row;
    }
}

// exact fp32 full-scan argmin for flagged rows, v5:
// grid (rowgroups, RSPLIT): block = 8 rows x 2048 codes (2 MB cbT chunk,
// L2-resident & shared across co-resident blocks). 512 thr, thread owns 4
// consecutive codes; cv software-pipelined (load d+1 before computing d).
// Cross-split merge via global atomicMin on packed (sortable-dist|idx).
__global__ void vq_recompute(const float* __restrict__ inp, const float* __restrict__ cbT,
                             const float* __restrict__ cn, const int* __restrict__ flaglist,
                             const int* __restrict__ cnt, u64* __restrict__ gmin2) {
    __shared__ float xsT[DIM][8];
    __shared__ u64 wred[8][8];
    const int tid = threadIdx.x;
    const int w = tid >> 6, lane = tid & 63;
    const int n = *cnt;
    const int base = blockIdx.x * 8;
    if (base >= n) return;

    // stage 8 rows transposed: wave w loads row (base+w), lane covers 4 dims
    {
        int li = base + w;
        int row = flaglist[li < n ? li : (n - 1)];
        float4 a = ((const float4*)(inp + (size_t)row * DIM))[lane];
        int d0 = lane * 4;
        xsT[d0 + 0][w] = a.x; xsT[d0 + 1][w] = a.y;
        xsT[d0 + 2][w] = a.z; xsT[d0 + 3][w] = a.w;
    }
    __syncthreads();

    const int cbase = blockIdx.y * (K_CODES / RSPLIT) + tid * 4;  // this thread's 4 codes
    float4 acc[8];
#pragma unroll
    for (int r = 0; r < 8; ++r) acc[r] = (float4){0.f, 0.f, 0.f, 0.f};

    float4 cv = *(const float4*)(cbT + cbase);      // d = 0
#pragma unroll 4
    for (int d = 0; d < DIM - 1; ++d) {
        float4 nx = *(const float4*)(cbT + (size_t)(d + 1) * K_CODES + cbase);
        float4 xa = *(const float4*)&xsT[d][0];
        float4 xb = *(const float4*)&xsT[d][4];
        float xv[8] = {xa.x, xa.y, xa.z, xa.w, xb.x, xb.y, xb.z, xb.w};
#pragma unroll
        for (int r = 0; r < 8; ++r) {
            acc[r].x = fmaf(xv[r], cv.x, acc[r].x);
            acc[r].y = fmaf(xv[r], cv.y, acc[r].y);
            acc[r].z = fmaf(xv[r], cv.z, acc[r].z);
            acc[r].w = fmaf(xv[r], cv.w, acc[r].w);
        }
        cv = nx;
    }
    {
        const int d = DIM - 1;
        float4 xa = *(const float4*)&xsT[d][0];
        float4 xb = *(const float4*)&xsT[d][4];
        float xv[8] = {xa.x, xa.y, xa.z, xa.w, xb.x, xb.y, xb.z, xb.w};
#pragma unroll
        for (int r = 0; r < 8; ++r) {
            acc[r].x = fmaf(xv[r], cv.x, acc[r].x);
            acc[r].y = fmaf(xv[r], cv.y, acc[r].y);
            acc[r].z = fmaf(xv[r], cv.z, acc[r].z);
            acc[r].w = fmaf(xv[r], cv.w, acc[r].w);
        }
    }

    u64 best[8];
    float4 cn4 = *(const float4*)(cn + cbase);
#pragma unroll
    for (int r = 0; r < 8; ++r) {
        float d0 = cn4.x - 2.0f * acc[r].x;
        float d1 = cn4.y - 2.0f * acc[r].y;
        float d2 = cn4.z - 2.0f * acc[r].z;
        float d3 = cn4.w - 2.0f * acc[r].w;
        u64 b = ((u64)sortable(d0) << 32) | (unsigned)(cbase + 0);
        b = u64min(b, ((u64)sortable(d1) << 32) | (unsigned)(cbase + 1));
        b = u64min(b, ((u64)sortable(d2) << 32) | (unsigned)(cbase + 2));
        b = u64min(b, ((u64)sortable(d3) << 32) | (unsigned)(cbase + 3));
        best[r] = b;
    }

    // reduce across 64 lanes, then across 8 waves, then atomicMin to global
#pragma unroll
    for (int m = 1; m <= 32; m <<= 1)
#pragma unroll
        for (int r = 0; r < 8; ++r) best[r] = u64min(best[r], shfl64x(best[r], m));
    if (lane < 8) wred[w][lane] = best[lane];
    __syncthreads();
    if (tid < 8 && base + tid < n) {
        u64 b = wred[0][tid];
#pragma unroll
        for (int ww = 1; ww < 8; ++ww) b = u64min(b, wred[ww][tid]);
        atomicMin(&gmin2[flaglist[base + tid]], b);
    }
}

// write recomputed indices back into idx32
__global__ void vq_writeback(const u64* __restrict__ gmin2, const int* __restrict__ flaglist,
                             const int* __restrict__ cnt, unsigned* __restrict__ idx32) {
    int i = blockIdx.x * 256 + threadIdx.x;
    if (i < *cnt) {
        int row = flaglist[i];
        idx32[row] = (unsigned)(gmin2[row] & 0xffffffffull);
    }
}

// gather codebook rows, write quantized + tokens, per-block loss partial, histogram
__global__ void vq_gather(const float* __restrict__ inp, const float* __restrict__ cb,
                          const unsigned* __restrict__ idx32, float* __restrict__ out,
                          float* __restrict__ losspart, unsigned int* __restrict__ hist) {
    __shared__ float red[4];
    int w = threadIdx.x >> 6, lane = threadIdx.x & 63;
    int i = blockIdx.x * 4 + w;
    unsigned idx = idx32[i];
    float4 c = ((const float4*)(cb + (size_t)idx * DIM))[lane];
    float4 x = ((const float4*)(inp + (size_t)i * DIM))[lane];
    ((float4*)(out + OUT_Q))[(size_t)i * 64 + lane] = c;
    float dx = c.x - x.x, dy = c.y - x.y, dz = c.z - x.z, dw = c.w - x.w;
    float s = dx * dx + dy * dy + dz * dz + dw * dw;
#pragma unroll
    for (int m = 32; m; m >>= 1) s += __shfl_xor(s, m, 64);
    if (lane == 0) {
        out[OUT_T + i] = (float)idx;
        red[w] = s;
        atomicAdd(&hist[idx], 1u);
    }
    __syncthreads();
    if (threadIdx.x == 0)
        losspart[blockIdx.x] = red[0] + red[1] + red[2] + red[3];
}

__global__ void vq_finalize(const unsigned int* __restrict__ hist,
                            const float* __restrict__ losspart, float* __restrict__ out) {
    __shared__ float redp[256], redl[256];
    int tid = threadIdx.x;
    float sp = 0.f, sl = 0.f;
    for (int k = tid; k < K_CODES; k += 256) {
        float p = (float)hist[k] * (1.0f / (float)N_ROWS);
        sp += p * logf(p + 1e-10f);
        sl += losspart[k];
    }
    redp[tid] = sp; redl[tid] = sl;
    __syncthreads();
    for (int st = 128; st; st >>= 1) {
        if (tid < st) { redp[tid] += redp[tid + st]; redl[tid] += redl[tid + st]; }
        __syncthreads();
    }
    if (tid == 0) {
        float perp = expf(-redp[0]);
        float e = redl[0] / 8388608.0f;      // mean((q - x)^2)
        out[OUT_S + 0] = 1.25f * e;          // vq_loss
        out[OUT_S + 1] = 0.25f * e;          // commitment_loss
        out[OUT_S + 2] = e;                  // codebook_loss
        out[OUT_S + 3] = perp;               // perplexity
    }
}

extern "C" void kernel_launch(void* const* d_in, const int* in_sizes, int n_in,
                              void* d_out, int out_size, void* d_ws, size_t ws_size,
                              hipStream_t stream) {
    const float* inp = (const float*)d_in[0];
    const float* cb = (const float*)d_in[1];
    float* out = (float*)d_out;
    char* ws = (char*)d_ws;
    u16* A = (u16*)(ws + A_OFF);
    u16* B = (u16*)(ws + B_OFF);
    float* cn = (float*)(ws + CN_OFF);
    u64* part1 = (u64*)(ws + PART1_OFF);
    float* part2 = (float*)(ws + PART2_OFF);
    unsigned* idx32 = (unsigned*)(ws + IDX_OFF);
    unsigned int* hist = (unsigned int*)(ws + HIST_OFF);
    int* cnt = (int*)(ws + CNT_OFF);
    int* flaglist = (int*)(ws + FLAG_OFF);
    float* losspart = (float*)(ws + LOSS_OFF);
    float* cbT = (float*)(ws + CBT_OFF);
    u64* gmin2 = (u64*)(ws + GMIN2_OFF);

    hipMemsetAsync(hist, 0, K_CODES * 4 + 16, stream);   // hist + cnt
    hipMemsetAsync(gmin2, 0xFF, N_ROWS * 8, stream);

    prep<<<5120, 256, 0, stream>>>(inp, cb, A, B, cn);
    transpose_cb<<<dim3(K_CODES / 64, DIM / 64), 256, 0, stream>>>(cb, cbT);
    vq_pass1<<<dim3(N_ROWS / BM, JSPLIT), 512, 0, stream>>>(A, B, cn, part1, part2);
    vq_merge<<<N_ROWS / 256, 256, 0, stream>>>(part1, part2, idx32, flaglist, cnt);
    vq_recompute<<<dim3(N_ROWS / 8, RSPLIT), 512, 0, stream>>>(inp, cbT, cn, flaglist, cnt, gmin2);
    vq_writeback<<<N_ROWS / 256, 256, 0, stream>>>(gmin2, flaglist, cnt, idx32);
    vq_gather<<<N_ROWS / 4, 256, 0, stream>>>(inp, cb, idx32, out, losspart, hist);
    vq_finalize<<<1, 256, 0, stream>>>(hist, losspart, out);
}